// Round 19
// baseline (161.848 us; speedup 1.0000x reference)
//
#include <hip/hip_runtime.h>

typedef __attribute__((ext_vector_type(8))) short short8;
typedef __attribute__((ext_vector_type(8))) __bf16 bf16x8;
typedef __attribute__((ext_vector_type(2))) __bf16 bf16x2;
typedef __attribute__((ext_vector_type(4))) float f32x4;
typedef __attribute__((ext_vector_type(2))) unsigned int uint2v;

#define LOG2E 1.44269504088896340736f

__device__ __forceinline__ unsigned short f2b(float f) {
  unsigned u = __builtin_bit_cast(unsigned, f);
  u += 0x7fffu + ((u >> 16) & 1u);
  return (unsigned short)(u >> 16);
}
__device__ __forceinline__ float b2f(unsigned short s) {
  unsigned u = (unsigned)s << 16;
  return __builtin_bit_cast(float, u);
}
__device__ __forceinline__ bf16x8 asbf(short8 s) { return __builtin_bit_cast(bf16x8, s); }

__device__ __forceinline__ void gl_lds16(const void* g, void* l) {
  __builtin_amdgcn_global_load_lds(
      (const __attribute__((address_space(1))) void*)g,
      (__attribute__((address_space(3))) void*)l, 16, 0, 0);
}

__device__ __forceinline__ unsigned lds_a(const void* p) {
  return (unsigned)(size_t)(__attribute__((address_space(3))) const void*)p;
}

__device__ __forceinline__ unsigned pk_bf16(float a, float b) {
  bf16x2 v;
  v[0] = (__bf16)a;
  v[1] = (__bf16)b;
  return __builtin_bit_cast(unsigned, v);
}

template <int N>
__device__ __forceinline__ void wait_vm() {
  if constexpr (N == 4) asm volatile("s_waitcnt vmcnt(4)" ::: "memory");
  else if constexpr (N == 1) asm volatile("s_waitcnt vmcnt(1)" ::: "memory");
  else asm volatile("s_waitcnt vmcnt(0)" ::: "memory");
}

// ---------- fused prep: x->bf16 cvt + both weight transposes ----------
__device__ __forceinline__ void transpose_tile(const float* __restrict__ W,
                                               unsigned short* __restrict__ Wt,
                                               int R, int C, int tc, int tr, int tid) {
  __shared__ float tile[64][65];
  const int r0 = tr * 64, c0 = tc * 64;
  for (int it = 0; it < 16; ++it) {
    int lin = it * 256 + tid;
    int r = lin >> 6, c = lin & 63;
    tile[r][c] = W[(size_t)(r0 + r) * C + c0 + c];
  }
  __syncthreads();
  for (int it = 0; it < 16; ++it) {
    int lin = it * 256 + tid;
    int orr = lin >> 6, oc = lin & 63;
    Wt[(size_t)(c0 + orr) * R + r0 + oc] = f2b(tile[oc][orr]);
  }
}

__global__ __launch_bounds__(256)
void k_prep(const float* __restrict__ x, unsigned short* __restrict__ xb,
            const float* __restrict__ Wa, unsigned short* __restrict__ Wat,
            const float* __restrict__ Wp, unsigned short* __restrict__ Wpt) {
  const int bid = blockIdx.x, tid = threadIdx.x;
  if (bid < 2048) {
    size_t i = ((size_t)bid * 256 + tid) * 16;
#pragma unroll
    for (int v = 0; v < 4; ++v) {
      float4 f = *(const float4*)(x + i + v * 4);
      ushort4 r;
      r.x = f2b(f.x); r.y = f2b(f.y); r.z = f2b(f.z); r.w = f2b(f.w);
      *(ushort4*)(xb + i + v * 4) = r;
    }
  } else if (bid < 2816) {
    int idx = bid - 2048;                       // W_attn [1024][3072] -> Wat [3072][1024]
    transpose_tile(Wa, Wat, 1024, 3072, idx % 48, idx / 48, tid);
  } else {
    int idx = bid - 2816;                       // W_proj [1024][1024] -> Wpt [1024][1024]
    transpose_tile(Wp, Wpt, 1024, 1024, idx % 16, idx / 16, tid);
  }
}

// ---------- BK=32 pipelined GEMM, BMx128 tile (R18 verified) ----------
// BM=256: 2 blocks/CU — big QKV GEMM. BM=128: 32 VGPR, 3-4/CU — proj GEMM.
template <int BM, bool OUT_BF16>
__global__ __launch_bounds__(512)
void k_gemm_bk32(const unsigned short* __restrict__ A, const unsigned short* __restrict__ Bt,
                 const float* __restrict__ bias, void* __restrict__ Cp,
                 int M, int N, int K) {
  constexpr int BNW = 32, NR = 2, BN = 128;
  constexpr int MQ = BM / 32;
  __shared__ unsigned short lds[2][(BM + BN) * 32];

  const int tid = threadIdx.x;
  const int lane = tid & 63;
  const int wv = tid >> 6;
  const int g = lane >> 4, l15 = lane & 15;
  const int wr = wv >> 2, wc = wv & 3;

  const int ntn = N / BN;
  const int nwg = gridDim.x;
  const int bid = blockIdx.x;
  const int cpx = nwg >> 3;
  const int swz = (bid & 7) * cpx + (bid >> 3);
  const int tm = swz / ntn, tn = swz % ntn;

  const unsigned short* Ab = A + (size_t)(tm * BM) * K;
  const unsigned short* Bb = Bt + (size_t)(tn * BN) * K;

  const int NT = K >> 5;

  auto As = [&](int buf) -> char* { return (char*)&lds[buf][0]; };
  auto Bs = [&](int buf) -> char* { return (char*)&lds[buf][BM * 32]; };

  auto stageA = [&](int buf, int t) {
#pragma unroll
    for (int it = 0; it < BM / 128; ++it) {
      int cidx = it * 512 + tid;
      int row = cidx >> 2, c8 = cidx & 3;
      int sc = c8 ^ ((row >> 1) & 3);
      gl_lds16(Ab + (size_t)row * K + t * 32 + sc * 8, As(buf) + cidx * 16);
    }
  };
  auto stageB = [&](int buf, int t) {
    int cidx = tid;
    int row = cidx >> 2, c8 = cidx & 3;
    int sc = c8 ^ ((row >> 1) & 3);
    gl_lds16(Bb + (size_t)row * K + t * 32 + sc * 8, Bs(buf) + cidx * 16);
  };

  auto rdA = [&](int buf, int ms) -> short8 {
    int row = wr * (BM / 2) + ms * 16 + l15;
    int ch = g ^ ((row >> 1) & 3);
    return *(const short8*)(As(buf) + row * 64 + ch * 16);
  };
  auto rdB = [&](int buf, int n) -> short8 {
    int row = wc * BNW + n * 16 + l15;
    int ch = g ^ ((row >> 1) & 3);
    return *(const short8*)(Bs(buf) + row * 64 + ch * 16);
  };

  f32x4 acc[MQ][NR] = {};

  stageA(0, 0);
  stageB(0, 0);
  stageB(1, 1);
  wait_vm<1>();
  __builtin_amdgcn_s_barrier();

  for (int t = 0; t < NT; ++t) {
    const int buf = t & 1, nbuf = buf ^ 1;
    short8 bfr[NR], a0, a1;

    // ---- alpha ----
    if (t + 1 < NT) stageA(nbuf, t + 1);
#pragma unroll
    for (int n = 0; n < NR; ++n) bfr[n] = rdB(buf, n);
    a0 = rdA(buf, 0);
    a1 = rdA(buf, 1);
    asm volatile("s_waitcnt lgkmcnt(0)" ::: "memory");
    __builtin_amdgcn_sched_barrier(0);
    __builtin_amdgcn_s_barrier();
    __builtin_amdgcn_s_setprio(1);
#pragma unroll
    for (int n = 0; n < NR; ++n) {
      acc[0][n] = __builtin_amdgcn_mfma_f32_16x16x32_bf16(asbf(a0), asbf(bfr[n]), acc[0][n], 0, 0, 0);
      acc[1][n] = __builtin_amdgcn_mfma_f32_16x16x32_bf16(asbf(a1), asbf(bfr[n]), acc[1][n], 0, 0, 0);
    }
    if constexpr (MQ == 8) {
      a0 = rdA(buf, 2);
      a1 = rdA(buf, 3);
#pragma unroll
      for (int n = 0; n < NR; ++n) {
        acc[2][n] = __builtin_amdgcn_mfma_f32_16x16x32_bf16(asbf(a0), asbf(bfr[n]), acc[2][n], 0, 0, 0);
        acc[3][n] = __builtin_amdgcn_mfma_f32_16x16x32_bf16(asbf(a1), asbf(bfr[n]), acc[3][n], 0, 0, 0);
      }
    }
    __builtin_amdgcn_s_setprio(0);

    // ---- beta ----
    if (t + 2 < NT) stageB(buf, t + 2);
    a0 = rdA(buf, MQ / 2);
    a1 = rdA(buf, MQ / 2 + 1);
    asm volatile("s_waitcnt lgkmcnt(0)" ::: "memory");
    __builtin_amdgcn_sched_barrier(0);
    __builtin_amdgcn_s_barrier();
    __builtin_amdgcn_s_setprio(1);
#pragma unroll
    for (int n = 0; n < NR; ++n) {
      acc[MQ / 2][n] =
          __builtin_amdgcn_mfma_f32_16x16x32_bf16(asbf(a0), asbf(bfr[n]), acc[MQ / 2][n], 0, 0, 0);
      acc[MQ / 2 + 1][n] =
          __builtin_amdgcn_mfma_f32_16x16x32_bf16(asbf(a1), asbf(bfr[n]), acc[MQ / 2 + 1][n], 0, 0, 0);
    }
    if constexpr (MQ == 8) {
      a0 = rdA(buf, 6);
      a1 = rdA(buf, 7);
#pragma unroll
      for (int n = 0; n < NR; ++n) {
        acc[6][n] = __builtin_amdgcn_mfma_f32_16x16x32_bf16(asbf(a0), asbf(bfr[n]), acc[6][n], 0, 0, 0);
        acc[7][n] = __builtin_amdgcn_mfma_f32_16x16x32_bf16(asbf(a1), asbf(bfr[n]), acc[7][n], 0, 0, 0);
      }
    }
    __builtin_amdgcn_s_setprio(0);
    if (t + 2 < NT) wait_vm<1>();
    else            wait_vm<0>();
    __builtin_amdgcn_s_barrier();
  }

  const int crow0 = tm * BM + wr * (BM / 2) + g * 4;
  const int ccol0 = tn * BN + wc * BNW + l15;
#pragma unroll
  for (int n = 0; n < NR; ++n) {
    int col = ccol0 + n * 16;
    float bv = bias[col];
#pragma unroll
    for (int mq = 0; mq < MQ; ++mq)
#pragma unroll
      for (int j = 0; j < 4; ++j) {
        int row = crow0 + mq * 16 + j;
        float v = acc[mq][n][j] + bv;
        if constexpr (OUT_BF16)
          ((unsigned short*)Cp)[(size_t)row * N + col] = f2b(v);
        else
          ((float*)Cp)[(size_t)row * N + col] = v;
      }
  }
}

// ---------- causal flash attention, KVBLK=128 ----------
// R13 structure; l via VALU psum (folded into exp loop) instead of ones-MFMA:
// saves 8 MFMA/chunk on the PV serial path; psum adds hide under v_exp chain.
__global__ __launch_bounds__(512)
void k_attn(const unsigned short* __restrict__ qkv, unsigned short* __restrict__ y) {
  constexpr int SEQ = 2048, TD = 3072, DM = 1024;
  __shared__ unsigned short Kl[2][8192];
  __shared__ unsigned short Vl[2][8192];
  __shared__ unsigned short Pl[8][4096];

  const int f = blockIdx.x;                 // 0..255
  const int wrk = (f & 7) * 32 + (f >> 3);  // XCD-contiguous bh
  const int bh = wrk >> 2, pr = wrk & 3;
  const int b = bh >> 4, h = bh & 15;
  const int tid = threadIdx.x;
  const int lane = tid & 63, w = tid >> 6;
  const int g = lane >> 4, l15 = lane & 15;

  const size_t base = (size_t)b * SEQ * TD + h * 64;
  const unsigned short* Kg0 = qkv + base + 1024;
  const unsigned short* Vg0 = qkv + base + 2048;

  auto stage = [&](int buf, int c) {
    const unsigned short* Kg = Kg0 + (size_t)(c * 128) * TD;
    const unsigned short* Vg = Vg0 + (size_t)(c * 128) * TD;
#pragma unroll
    for (int it = 0; it < 2; ++it) {
      int j = it * 512 + tid;  // 0..1023
      int r = j >> 3, cc = j & 7;
      int cck = cc ^ (r & 7);
      gl_lds16(Kg + (size_t)r * TD + cck * 8, (char*)Kl[buf] + j * 16);
      int kv = ((j >> 1) & 3) | (((j >> 5) & 1) << 2) | (((j >> 3) & 3) << 3) |
               (((j >> 6) & 1) << 5) | ((j >> 9) << 6);
      int d0 = (((j >> 7) & 3) << 4) | ((j & 1) << 3);
      gl_lds16(Vg + (size_t)kv * TD + d0, (char*)Vl[buf] + j * 16);
    }
  };

  char* pw = (char*)Pl + w * 8192;

  for (int half = 0; half < 2; ++half) {
    const int qt = half ? (7 - pr) : pr;
    const int q0 = qt * 256;
    const int qw = w * 32;

    short8 qf[2][2];
#pragma unroll
    for (int qg = 0; qg < 2; ++qg) {
      const unsigned short* qrow = qkv + base + (size_t)(q0 + qw + qg * 16 + l15) * TD;
#pragma unroll
      for (int kh = 0; kh < 2; ++kh) {
        short8 t = *(const short8*)(qrow + kh * 32 + g * 8);
#pragma unroll
        for (int i = 0; i < 8; ++i)
          t[i] = (short)f2b(b2f((unsigned short)t[i]) * (0.125f * LOG2E));
        qf[qg][kh] = t;
      }
    }

    f32x4 o[2][4] = {};
    float l_run[2] = {0.f, 0.f};  // per-lane row-sum for q = l15 (g-duplicated)

    const int nch = 2 * (qt + 1);
    int cur = 0;
    stage(0, 0);
    for (int c = 0; c < nch; ++c) {
      if (c + 1 < nch) {
        stage(cur ^ 1, c + 1);
        wait_vm<4>();
      } else {
        wait_vm<0>();
      }
      __builtin_amdgcn_s_barrier();

      f32x4 sv[2][8];
      __builtin_amdgcn_s_setprio(1);
#pragma unroll
      for (int ff = 0; ff < 8; ++ff) {
        int kv = ff * 16 + l15;
        short8 kf0 = *(const short8*)((const char*)Kl[cur] + kv * 128 + ((g) ^ (kv & 7)) * 16);
        short8 kf1 = *(const short8*)((const char*)Kl[cur] + kv * 128 + ((4 + g) ^ (kv & 7)) * 16);
#pragma unroll
        for (int qg = 0; qg < 2; ++qg) {
          f32x4 s = {};
          s = __builtin_amdgcn_mfma_f32_16x16x32_bf16(asbf(kf0), asbf(qf[qg][0]), s, 0, 0, 0);
          s = __builtin_amdgcn_mfma_f32_16x16x32_bf16(asbf(kf1), asbf(qf[qg][1]), s, 0, 0, 0);
          sv[qg][ff] = s;
        }
      }
      __builtin_amdgcn_s_setprio(0);

      const int crel = c - 2 * qt;
      if (crel >= 0) {  // diagonal chunks: mask kv > q
#pragma unroll
        for (int qg = 0; qg < 2; ++qg)
#pragma unroll
          for (int ff = 0; ff < 8; ++ff)
#pragma unroll
            for (int r = 0; r < 4; ++r)
              if (crel * 128 + ff * 16 + g * 4 + r > qw + qg * 16 + l15)
                sv[qg][ff][r] = -128.f;
      }

      // p = exp2(s); psum accumulates during exp (lane's row q = l15)
#pragma unroll
      for (int qg = 0; qg < 2; ++qg) {
        float psum = 0.f;
#pragma unroll
        for (int ff = 0; ff < 8; ++ff) {
          float p0 = __builtin_amdgcn_exp2f(sv[qg][ff][0]);
          float p1 = __builtin_amdgcn_exp2f(sv[qg][ff][1]);
          float p2 = __builtin_amdgcn_exp2f(sv[qg][ff][2]);
          float p3 = __builtin_amdgcn_exp2f(sv[qg][ff][3]);
          psum += (p0 + p1) + (p2 + p3);
          unsigned w0 = pk_bf16(p0, p1);
          unsigned w1 = pk_bf16(p2, p3);
          unsigned long long pk = (unsigned long long)w0 | ((unsigned long long)w1 << 32);
          int off = (ff >> 2) * 4096 + qg * 2048 +
                    ((l15 * 128 + (ff & 3) * 32 + g * 8) ^ ((l15 & 7) << 4));
          *(unsigned long long*)(pw + off) = pk;
        }
        psum += __shfl_xor(psum, 16);
        psum += __shfl_xor(psum, 32);
        l_run[qg] += psum;
      }

      const unsigned vaddr = lds_a((const char*)Vl[cur] + g * 128 + l15 * 8);
#pragma unroll
      for (int kvh = 0; kvh < 4; ++kvh) {
        const int sub = kvh >> 1, kvl = kvh & 1;
        uint2v t0[4], t1[4];
#pragma unroll
        for (int n = 0; n < 4; ++n) {
          asm volatile("ds_read_b64_tr_b16 %0, %1 offset:%2"
                       : "=v"(t0[n]) : "v"(vaddr), "i"(sub * 8192 + n * 2048 + kvl * 1024));
          asm volatile("ds_read_b64_tr_b16 %0, %1 offset:%2"
                       : "=v"(t1[n]) : "v"(vaddr), "i"(sub * 8192 + n * 2048 + kvl * 1024 + 512));
        }
        asm volatile("s_waitcnt lgkmcnt(0)" ::: "memory");
        __builtin_amdgcn_sched_barrier(0);
        __builtin_amdgcn_s_setprio(1);
#pragma unroll
        for (int qg = 0; qg < 2; ++qg) {
          short8 pa = *(const short8*)(pw + sub * 4096 + qg * 2048 +
                                       ((l15 * 128 + kvl * 64 + g * 16) ^ ((l15 & 7) << 4)));
#pragma unroll
          for (int n = 0; n < 4; ++n) {
            union { uint2v u[2]; short8 s; } uu;
            uu.u[0] = t0[n]; uu.u[1] = t1[n];
            o[qg][n] = __builtin_amdgcn_mfma_f32_16x16x32_bf16(asbf(pa), asbf(uu.s),
                                                               o[qg][n], 0, 0, 0);
          }
        }
        __builtin_amdgcn_s_setprio(0);
      }

      __builtin_amdgcn_s_barrier();
      cur ^= 1;
    }

#pragma unroll
    for (int qg = 0; qg < 2; ++qg) {
      float lj[4];
#pragma unroll
      for (int j = 0; j < 4; ++j) lj[j] = 1.f / __shfl(l_run[qg], g * 4 + j);
#pragma unroll
      for (int n = 0; n < 4; ++n)
#pragma unroll
        for (int j = 0; j < 4; ++j) {
          int row = q0 + qw + qg * 16 + g * 4 + j;
          int col = h * 64 + n * 16 + l15;
          y[(size_t)(b * SEQ + row) * DM + col] = f2b(o[qg][n][j] * lj[j]);
        }
    }
  }
}

extern "C" void kernel_launch(void* const* d_in, const int* in_sizes, int n_in,
                              void* d_out, int out_size, void* d_ws, size_t ws_size,
                              hipStream_t stream) {
  const float* x = (const float*)d_in[0];
  const float* W_attn = (const float*)d_in[1];
  const float* b_attn = (const float*)d_in[2];
  const float* W_proj = (const float*)d_in[3];
  const float* b_proj = (const float*)d_in[4];
  float* out = (float*)d_out;

  const int B = 4, S = 2048, D = 1024;
  const int M = B * S;   // 8192
  const int TD = 3 * D;  // 3072

  char* ws = (char*)d_ws;
  unsigned short* qkvb = (unsigned short*)ws;                                 // 48 MB
  unsigned short* xb = (unsigned short*)(ws + (size_t)M * TD * 2);            // 16 MB (reused as y)
  unsigned short* Wat = (unsigned short*)(ws + (size_t)M * TD * 2 + (size_t)M * D * 2);
  unsigned short* Wpt = Wat + (size_t)TD * D;

  k_prep<<<3072, 256, 0, stream>>>(x, xb, W_attn, Wat, W_proj, Wpt);
  k_gemm_bk32<256, true><<<(M / 256) * (TD / 128), 512, 0, stream>>>(xb, Wat, b_attn, qkvb, M, TD, D);
  k_attn<<<256, 512, 0, stream>>>(qkvb, xb);  // y overwrites xb
  k_gemm_bk32<128, false><<<(M / 128) * (D / 128), 512, 0, stream>>>(xb, Wpt, b_proj, out, M, D, D);
}

// Round 20
// 158.904 us; speedup vs baseline: 1.0185x; 1.0185x over previous
//
#include <hip/hip_runtime.h>

typedef __attribute__((ext_vector_type(8))) short short8;
typedef __attribute__((ext_vector_type(8))) __bf16 bf16x8;
typedef __attribute__((ext_vector_type(2))) __bf16 bf16x2;
typedef __attribute__((ext_vector_type(4))) float f32x4;
typedef __attribute__((ext_vector_type(2))) unsigned int uint2v;

#define LOG2E 1.44269504088896340736f

__device__ __forceinline__ unsigned short f2b(float f) {
  unsigned u = __builtin_bit_cast(unsigned, f);
  u += 0x7fffu + ((u >> 16) & 1u);
  return (unsigned short)(u >> 16);
}
__device__ __forceinline__ float b2f(unsigned short s) {
  unsigned u = (unsigned)s << 16;
  return __builtin_bit_cast(float, u);
}
__device__ __forceinline__ bf16x8 asbf(short8 s) { return __builtin_bit_cast(bf16x8, s); }

__device__ __forceinline__ void gl_lds16(const void* g, void* l) {
  __builtin_amdgcn_global_load_lds(
      (const __attribute__((address_space(1))) void*)g,
      (__attribute__((address_space(3))) void*)l, 16, 0, 0);
}

__device__ __forceinline__ unsigned lds_a(const void* p) {
  return (unsigned)(size_t)(__attribute__((address_space(3))) const void*)p;
}

__device__ __forceinline__ unsigned pk_bf16(float a, float b) {
  bf16x2 v;
  v[0] = (__bf16)a;
  v[1] = (__bf16)b;
  return __builtin_bit_cast(unsigned, v);
}

template <int N>
__device__ __forceinline__ void wait_vm() {
  if constexpr (N == 4) asm volatile("s_waitcnt vmcnt(4)" ::: "memory");
  else if constexpr (N == 1) asm volatile("s_waitcnt vmcnt(1)" ::: "memory");
  else asm volatile("s_waitcnt vmcnt(0)" ::: "memory");
}

// ---------- fused prep: x->bf16 cvt + both weight transposes ----------
__device__ __forceinline__ void transpose_tile(const float* __restrict__ W,
                                               unsigned short* __restrict__ Wt,
                                               int R, int C, int tc, int tr, int tid) {
  __shared__ float tile[64][65];
  const int r0 = tr * 64, c0 = tc * 64;
  for (int it = 0; it < 16; ++it) {
    int lin = it * 256 + tid;
    int r = lin >> 6, c = lin & 63;
    tile[r][c] = W[(size_t)(r0 + r) * C + c0 + c];
  }
  __syncthreads();
  for (int it = 0; it < 16; ++it) {
    int lin = it * 256 + tid;
    int orr = lin >> 6, oc = lin & 63;
    Wt[(size_t)(c0 + orr) * R + r0 + oc] = f2b(tile[oc][orr]);
  }
}

__global__ __launch_bounds__(256)
void k_prep(const float* __restrict__ x, unsigned short* __restrict__ xb,
            const float* __restrict__ Wa, unsigned short* __restrict__ Wat,
            const float* __restrict__ Wp, unsigned short* __restrict__ Wpt) {
  const int bid = blockIdx.x, tid = threadIdx.x;
  if (bid < 2048) {
    size_t i = ((size_t)bid * 256 + tid) * 16;
#pragma unroll
    for (int v = 0; v < 4; ++v) {
      float4 f = *(const float4*)(x + i + v * 4);
      ushort4 r;
      r.x = f2b(f.x); r.y = f2b(f.y); r.z = f2b(f.z); r.w = f2b(f.w);
      *(ushort4*)(xb + i + v * 4) = r;
    }
  } else if (bid < 2816) {
    int idx = bid - 2048;                       // W_attn [1024][3072] -> Wat [3072][1024]
    transpose_tile(Wa, Wat, 1024, 3072, idx % 48, idx / 48, tid);
  } else {
    int idx = bid - 2816;                       // W_proj [1024][1024] -> Wpt [1024][1024]
    transpose_tile(Wp, Wpt, 1024, 1024, idx % 16, idx / 16, tid);
  }
}

// ---------- BK=32 pipelined GEMM, BMx128 tile ----------
// BM=256: 2 blocks/CU, best for the big QKV GEMM (R16: 65.4us, 0 conflicts).
// BM=128: 32 VGPR, 3-4 blocks/CU — best for the small L2-resident proj GEMM.
// Pipeline (race-audited; vmcnt(1) drains tile-(t+1) operands, leaves B(t+2)):
//   alpha: stageA(t+1)->nbuf ; read B + first A pair(s) ; lgkm0 ; BAR ; mfma
//   beta : stageB(t+2)->buf  ; read second A pair(s) ; lgkm0 ; BAR ; mfma ;
//          vmcnt(1) ; BAR
template <int BM, bool OUT_BF16>
__global__ __launch_bounds__(512)
void k_gemm_bk32(const unsigned short* __restrict__ A, const unsigned short* __restrict__ Bt,
                 const float* __restrict__ bias, void* __restrict__ Cp,
                 int M, int N, int K) {
  constexpr int BNW = 32, NR = 2, BN = 128;
  constexpr int MQ = BM / 32;
  __shared__ unsigned short lds[2][(BM + BN) * 32];

  const int tid = threadIdx.x;
  const int lane = tid & 63;
  const int wv = tid >> 6;
  const int g = lane >> 4, l15 = lane & 15;
  const int wr = wv >> 2, wc = wv & 3;

  const int ntn = N / BN;
  const int nwg = gridDim.x;
  const int bid = blockIdx.x;
  const int cpx = nwg >> 3;
  const int swz = (bid & 7) * cpx + (bid >> 3);
  const int tm = swz / ntn, tn = swz % ntn;

  const unsigned short* Ab = A + (size_t)(tm * BM) * K;
  const unsigned short* Bb = Bt + (size_t)(tn * BN) * K;

  const int NT = K >> 5;

  auto As = [&](int buf) -> char* { return (char*)&lds[buf][0]; };
  auto Bs = [&](int buf) -> char* { return (char*)&lds[buf][BM * 32]; };

  auto stageA = [&](int buf, int t) {
#pragma unroll
    for (int it = 0; it < BM / 128; ++it) {
      int cidx = it * 512 + tid;
      int row = cidx >> 2, c8 = cidx & 3;
      int sc = c8 ^ ((row >> 1) & 3);
      gl_lds16(Ab + (size_t)row * K + t * 32 + sc * 8, As(buf) + cidx * 16);
    }
  };
  auto stageB = [&](int buf, int t) {
    int cidx = tid;
    int row = cidx >> 2, c8 = cidx & 3;
    int sc = c8 ^ ((row >> 1) & 3);
    gl_lds16(Bb + (size_t)row * K + t * 32 + sc * 8, Bs(buf) + cidx * 16);
  };

  auto rdA = [&](int buf, int ms) -> short8 {
    int row = wr * (BM / 2) + ms * 16 + l15;
    int ch = g ^ ((row >> 1) & 3);
    return *(const short8*)(As(buf) + row * 64 + ch * 16);
  };
  auto rdB = [&](int buf, int n) -> short8 {
    int row = wc * BNW + n * 16 + l15;
    int ch = g ^ ((row >> 1) & 3);
    return *(const short8*)(Bs(buf) + row * 64 + ch * 16);
  };

  f32x4 acc[MQ][NR] = {};

  stageA(0, 0);
  stageB(0, 0);
  stageB(1, 1);
  wait_vm<1>();
  __builtin_amdgcn_s_barrier();

  for (int t = 0; t < NT; ++t) {
    const int buf = t & 1, nbuf = buf ^ 1;
    short8 bfr[NR], a0, a1;

    // ---- alpha: m-subtiles [0, MQ/2) ----
    if (t + 1 < NT) stageA(nbuf, t + 1);
#pragma unroll
    for (int n = 0; n < NR; ++n) bfr[n] = rdB(buf, n);
    a0 = rdA(buf, 0);
    a1 = rdA(buf, 1);
    asm volatile("s_waitcnt lgkmcnt(0)" ::: "memory");
    __builtin_amdgcn_sched_barrier(0);
    __builtin_amdgcn_s_barrier();
    __builtin_amdgcn_s_setprio(1);
#pragma unroll
    for (int n = 0; n < NR; ++n) {
      acc[0][n] = __builtin_amdgcn_mfma_f32_16x16x32_bf16(asbf(a0), asbf(bfr[n]), acc[0][n], 0, 0, 0);
      acc[1][n] = __builtin_amdgcn_mfma_f32_16x16x32_bf16(asbf(a1), asbf(bfr[n]), acc[1][n], 0, 0, 0);
    }
    if constexpr (MQ == 8) {
      a0 = rdA(buf, 2);
      a1 = rdA(buf, 3);
#pragma unroll
      for (int n = 0; n < NR; ++n) {
        acc[2][n] = __builtin_amdgcn_mfma_f32_16x16x32_bf16(asbf(a0), asbf(bfr[n]), acc[2][n], 0, 0, 0);
        acc[3][n] = __builtin_amdgcn_mfma_f32_16x16x32_bf16(asbf(a1), asbf(bfr[n]), acc[3][n], 0, 0, 0);
      }
    }
    __builtin_amdgcn_s_setprio(0);

    // ---- beta: m-subtiles [MQ/2, MQ) ----
    if (t + 2 < NT) stageB(buf, t + 2);
    a0 = rdA(buf, MQ / 2);
    a1 = rdA(buf, MQ / 2 + 1);
    asm volatile("s_waitcnt lgkmcnt(0)" ::: "memory");
    __builtin_amdgcn_sched_barrier(0);
    __builtin_amdgcn_s_barrier();
    __builtin_amdgcn_s_setprio(1);
#pragma unroll
    for (int n = 0; n < NR; ++n) {
      acc[MQ / 2][n] =
          __builtin_amdgcn_mfma_f32_16x16x32_bf16(asbf(a0), asbf(bfr[n]), acc[MQ / 2][n], 0, 0, 0);
      acc[MQ / 2 + 1][n] =
          __builtin_amdgcn_mfma_f32_16x16x32_bf16(asbf(a1), asbf(bfr[n]), acc[MQ / 2 + 1][n], 0, 0, 0);
    }
    if constexpr (MQ == 8) {
      a0 = rdA(buf, 6);
      a1 = rdA(buf, 7);
#pragma unroll
      for (int n = 0; n < NR; ++n) {
        acc[6][n] = __builtin_amdgcn_mfma_f32_16x16x32_bf16(asbf(a0), asbf(bfr[n]), acc[6][n], 0, 0, 0);
        acc[7][n] = __builtin_amdgcn_mfma_f32_16x16x32_bf16(asbf(a1), asbf(bfr[n]), acc[7][n], 0, 0, 0);
      }
    }
    __builtin_amdgcn_s_setprio(0);
    if (t + 2 < NT) wait_vm<1>();
    else            wait_vm<0>();
    __builtin_amdgcn_s_barrier();
  }

  const int crow0 = tm * BM + wr * (BM / 2) + g * 4;
  const int ccol0 = tn * BN + wc * BNW + l15;
#pragma unroll
  for (int n = 0; n < NR; ++n) {
    int col = ccol0 + n * 16;
    float bv = bias[col];
#pragma unroll
    for (int mq = 0; mq < MQ; ++mq)
#pragma unroll
      for (int j = 0; j < 4; ++j) {
        int row = crow0 + mq * 16 + j;
        float v = acc[mq][n][j] + bv;
        if constexpr (OUT_BF16)
          ((unsigned short*)Cp)[(size_t)row * N + col] = f2b(v);
        else
          ((float*)Cp)[(size_t)row * N + col] = v;
      }
  }
}

// ---------- causal flash attention, KVBLK=128 (R13/R18 verified) ----------
__global__ __launch_bounds__(512)
void k_attn(const unsigned short* __restrict__ qkv, unsigned short* __restrict__ y) {
  constexpr int SEQ = 2048, TD = 3072, DM = 1024;
  __shared__ unsigned short Kl[2][8192];
  __shared__ unsigned short Vl[2][8192];
  __shared__ unsigned short Pl[8][4096];

  const int f = blockIdx.x;                 // 0..255
  const int wrk = (f & 7) * 32 + (f >> 3);  // XCD-contiguous bh
  const int bh = wrk >> 2, pr = wrk & 3;
  const int b = bh >> 4, h = bh & 15;
  const int tid = threadIdx.x;
  const int lane = tid & 63, w = tid >> 6;
  const int g = lane >> 4, l15 = lane & 15;

  const size_t base = (size_t)b * SEQ * TD + h * 64;
  const unsigned short* Kg0 = qkv + base + 1024;
  const unsigned short* Vg0 = qkv + base + 2048;

  short8 onesb;
#pragma unroll
  for (int i = 0; i < 8; ++i) onesb[i] = (short)0x3F80;

  auto stage = [&](int buf, int c) {
    const unsigned short* Kg = Kg0 + (size_t)(c * 128) * TD;
    const unsigned short* Vg = Vg0 + (size_t)(c * 128) * TD;
#pragma unroll
    for (int it = 0; it < 2; ++it) {
      int j = it * 512 + tid;  // 0..1023
      int r = j >> 3, cc = j & 7;
      int cck = cc ^ (r & 7);
      gl_lds16(Kg + (size_t)r * TD + cck * 8, (char*)Kl[buf] + j * 16);
      int kv = ((j >> 1) & 3) | (((j >> 5) & 1) << 2) | (((j >> 3) & 3) << 3) |
               (((j >> 6) & 1) << 5) | ((j >> 9) << 6);
      int d0 = (((j >> 7) & 3) << 4) | ((j & 1) << 3);
      gl_lds16(Vg + (size_t)kv * TD + d0, (char*)Vl[buf] + j * 16);
    }
  };

  char* pw = (char*)Pl + w * 8192;

  for (int half = 0; half < 2; ++half) {
    const int qt = half ? (7 - pr) : pr;
    const int q0 = qt * 256;
    const int qw = w * 32;

    short8 qf[2][2];
#pragma unroll
    for (int qg = 0; qg < 2; ++qg) {
      const unsigned short* qrow = qkv + base + (size_t)(q0 + qw + qg * 16 + l15) * TD;
#pragma unroll
      for (int kh = 0; kh < 2; ++kh) {
        short8 t = *(const short8*)(qrow + kh * 32 + g * 8);
#pragma unroll
        for (int i = 0; i < 8; ++i)
          t[i] = (short)f2b(b2f((unsigned short)t[i]) * (0.125f * LOG2E));
        qf[qg][kh] = t;
      }
    }

    f32x4 o[2][4] = {};
    f32x4 ol[2] = {};

    const int nch = 2 * (qt + 1);
    int cur = 0;
    stage(0, 0);
    for (int c = 0; c < nch; ++c) {
      if (c + 1 < nch) {
        stage(cur ^ 1, c + 1);
        wait_vm<4>();
      } else {
        wait_vm<0>();
      }
      __builtin_amdgcn_s_barrier();

      f32x4 sv[2][8];
      __builtin_amdgcn_s_setprio(1);
#pragma unroll
      for (int ff = 0; ff < 8; ++ff) {
        int kv = ff * 16 + l15;
        short8 kf0 = *(const short8*)((const char*)Kl[cur] + kv * 128 + ((g) ^ (kv & 7)) * 16);
        short8 kf1 = *(const short8*)((const char*)Kl[cur] + kv * 128 + ((4 + g) ^ (kv & 7)) * 16);
#pragma unroll
        for (int qg = 0; qg < 2; ++qg) {
          f32x4 s = {};
          s = __builtin_amdgcn_mfma_f32_16x16x32_bf16(asbf(kf0), asbf(qf[qg][0]), s, 0, 0, 0);
          s = __builtin_amdgcn_mfma_f32_16x16x32_bf16(asbf(kf1), asbf(qf[qg][1]), s, 0, 0, 0);
          sv[qg][ff] = s;
        }
      }
      __builtin_amdgcn_s_setprio(0);

      const int crel = c - 2 * qt;
      if (crel >= 0) {
#pragma unroll
        for (int qg = 0; qg < 2; ++qg)
#pragma unroll
          for (int ff = 0; ff < 8; ++ff)
#pragma unroll
            for (int r = 0; r < 4; ++r)
              if (crel * 128 + ff * 16 + g * 4 + r > qw + qg * 16 + l15)
                sv[qg][ff][r] = -128.f;
      }

#pragma unroll
      for (int qg = 0; qg < 2; ++qg)
#pragma unroll
        for (int ff = 0; ff < 8; ++ff) {
          float p0 = __builtin_amdgcn_exp2f(sv[qg][ff][0]);
          float p1 = __builtin_amdgcn_exp2f(sv[qg][ff][1]);
          float p2 = __builtin_amdgcn_exp2f(sv[qg][ff][2]);
          float p3 = __builtin_amdgcn_exp2f(sv[qg][ff][3]);
          unsigned w0 = pk_bf16(p0, p1);
          unsigned w1 = pk_bf16(p2, p3);
          unsigned long long pk = (unsigned long long)w0 | ((unsigned long long)w1 << 32);
          int off = (ff >> 2) * 4096 + qg * 2048 +
                    ((l15 * 128 + (ff & 3) * 32 + g * 8) ^ ((l15 & 7) << 4));
          *(unsigned long long*)(pw + off) = pk;
        }

      const unsigned vaddr = lds_a((const char*)Vl[cur] + g * 128 + l15 * 8);
#pragma unroll
      for (int kvh = 0; kvh < 4; ++kvh) {
        const int sub = kvh >> 1, kvl = kvh & 1;
        uint2v t0[4], t1[4];
#pragma unroll
        for (int n = 0; n < 4; ++n) {
          asm volatile("ds_read_b64_tr_b16 %0, %1 offset:%2"
                       : "=v"(t0[n]) : "v"(vaddr), "i"(sub * 8192 + n * 2048 + kvl * 1024));
          asm volatile("ds_read_b64_tr_b16 %0, %1 offset:%2"
                       : "=v"(t1[n]) : "v"(vaddr), "i"(sub * 8192 + n * 2048 + kvl * 1024 + 512));
        }
        asm volatile("s_waitcnt lgkmcnt(0)" ::: "memory");
        __builtin_amdgcn_sched_barrier(0);
        __builtin_amdgcn_s_setprio(1);
#pragma unroll
        for (int qg = 0; qg < 2; ++qg) {
          short8 pa = *(const short8*)(pw + sub * 4096 + qg * 2048 +
                                       ((l15 * 128 + kvl * 64 + g * 16) ^ ((l15 & 7) << 4)));
#pragma unroll
          for (int n = 0; n < 4; ++n) {
            union { uint2v u[2]; short8 s; } uu;
            uu.u[0] = t0[n]; uu.u[1] = t1[n];
            o[qg][n] = __builtin_amdgcn_mfma_f32_16x16x32_bf16(asbf(pa), asbf(uu.s),
                                                               o[qg][n], 0, 0, 0);
          }
          ol[qg] = __builtin_amdgcn_mfma_f32_16x16x32_bf16(asbf(pa), asbf(onesb),
                                                           ol[qg], 0, 0, 0);
        }
        __builtin_amdgcn_s_setprio(0);
      }

      __builtin_amdgcn_s_barrier();
      cur ^= 1;
    }

#pragma unroll
    for (int qg = 0; qg < 2; ++qg) {
      float lj[4];
#pragma unroll
      for (int j = 0; j < 4; ++j) lj[j] = 1.f / ol[qg][j];
#pragma unroll
      for (int n = 0; n < 4; ++n)
#pragma unroll
        for (int j = 0; j < 4; ++j) {
          int row = q0 + qw + qg * 16 + g * 4 + j;
          int col = h * 64 + n * 16 + l15;
          y[(size_t)(b * SEQ + row) * DM + col] = f2b(o[qg][n][j] * lj[j]);
        }
    }
  }
}

extern "C" void kernel_launch(void* const* d_in, const int* in_sizes, int n_in,
                              void* d_out, int out_size, void* d_ws, size_t ws_size,
                              hipStream_t stream) {
  const float* x = (const float*)d_in[0];
  const float* W_attn = (const float*)d_in[1];
  const float* b_attn = (const float*)d_in[2];
  const float* W_proj = (const float*)d_in[3];
  const float* b_proj = (const float*)d_in[4];
  float* out = (float*)d_out;

  const int B = 4, S = 2048, D = 1024;
  const int M = B * S;   // 8192
  const int TD = 3 * D;  // 3072

  char* ws = (char*)d_ws;
  unsigned short* qkvb = (unsigned short*)ws;                                 // 48 MB
  unsigned short* xb = (unsigned short*)(ws + (size_t)M * TD * 2);            // 16 MB (reused as y)
  unsigned short* Wat = (unsigned short*)(ws + (size_t)M * TD * 2 + (size_t)M * D * 2);
  unsigned short* Wpt = Wat + (size_t)TD * D;

  k_prep<<<3072, 256, 0, stream>>>(x, xb, W_attn, Wat, W_proj, Wpt);
  k_gemm_bk32<256, true><<<(M / 256) * (TD / 128), 512, 0, stream>>>(xb, Wat, b_attn, qkvb, M, TD, D);
  k_attn<<<256, 512, 0, stream>>>(qkvb, xb);  // y overwrites xb
  k_gemm_bk32<128, false><<<(M / 128) * (D / 128), 512, 0, stream>>>(xb, Wpt, b_proj, out, M, D, D);
}